// Round 3
// baseline (216.818 us; speedup 1.0000x reference)
//
#include <hip/hip_runtime.h>
#include <hip/hip_bf16.h>
#include <math.h>

typedef unsigned short u16;
typedef __attribute__((ext_vector_type(8))) short bf16x8;
typedef __attribute__((ext_vector_type(4))) float f32x4;

constexpr int D_ = 1024;
constexpr int H_ = 1365;
constexpr int E_ = 7;
constexpr int NTOK = 2048;
constexpr int HP = 1408;          // H padded to multiple of 64 (BK)
constexpr int NE = 8;             // 7 routed + 1 shared
constexpr int SHARED_BASE = 4096;
constexpr int SLOTS = 6144;

#define CI_COUNT 0
#define CI_OFF   8

constexpr size_t WS_CTRL = 0;
constexpr size_t WS_TIDX = 256;
constexpr size_t WS_TW   = WS_TIDX + (size_t)NTOK*2*4;
constexpr size_t WS_PROB = WS_TW   + (size_t)NTOK*2*4;
constexpr size_t WS_LSE2 = WS_PROB + (size_t)NTOK*8*4;
constexpr size_t WS_STOK = WS_LSE2 + (size_t)NTOK*4;
constexpr size_t WS_SW   = WS_STOK + (size_t)SLOTS*4;
constexpr size_t WS_TSL  = WS_SW   + (size_t)SLOTS*4;
constexpr size_t WS_B1   = WS_TSL  + (size_t)NTOK*2*4;
constexpr size_t WS_B2   = WS_B1   + (size_t)NE*H_*4;
constexpr size_t WS_XB   = ((WS_B2 + (size_t)NE*D_*4) + 255) & ~(size_t)255;
constexpr size_t WS_W1B  = WS_XB  + (size_t)NTOK*D_*2;
constexpr size_t WS_W2B  = WS_W1B + (size_t)NE*H_*D_*2;
constexpr size_t WS_HEB  = WS_W2B + (size_t)NE*D_*HP*2;
constexpr size_t WS_Y    = WS_XB;   // y[SLOTS][D] fp32 aliases xb+w1b (dead after gemm1)

__device__ __forceinline__ u16 f2bf(float f) {
    __hip_bfloat16 h = __float2bfloat16(f);
    return __builtin_bit_cast(u16, h);
}

__device__ __forceinline__ void gload_lds16(const u16* g, u16* l) {
    __builtin_amdgcn_global_load_lds(
        (const __attribute__((address_space(1))) void*)g,
        (__attribute__((address_space(3))) void*)l, 16, 0, 0);
}

__device__ __forceinline__ uint4 pack8(float4 a, float4 b) {
    union { u16 h[8]; uint4 v; } u;
    u.h[0]=f2bf(a.x); u.h[1]=f2bf(a.y); u.h[2]=f2bf(a.z); u.h[3]=f2bf(a.w);
    u.h[4]=f2bf(b.x); u.h[5]=f2bf(b.y); u.h[6]=f2bf(b.z); u.h[7]=f2bf(b.w);
    return u.v;
}

// ---------------- convert fp32 -> bf16 staging buffers ----------------
__global__ void convert_kernel(const float* __restrict__ x,
                               const float* __restrict__ W1, const float* __restrict__ Ws1,
                               const float* __restrict__ W2, const float* __restrict__ Ws2,
                               const float* __restrict__ b1, const float* __restrict__ bs1,
                               const float* __restrict__ b2, const float* __restrict__ bs2,
                               u16* __restrict__ xb, u16* __restrict__ w1b, u16* __restrict__ w2b,
                               float* __restrict__ b1all, float* __restrict__ b2all)
{
    const size_t G0 = (size_t)NTOK*D_/8;
    const size_t G1 = (size_t)NE*H_*D_/8;
    const size_t G2 = (size_t)NE*D_*HP/8;
    const size_t W1FLAT = (size_t)7*H_*D_;
    const size_t SB = (size_t)NE*H_ + (size_t)NE*D_;
    const size_t total = G0+G1+G2+SB;
    for (size_t i = blockIdx.x*(size_t)blockDim.x + threadIdx.x; i < total;
         i += (size_t)gridDim.x*blockDim.x) {
        size_t k = i;
        if (k < G0) {
            const float4* s = (const float4*)x + k*2;
            ((uint4*)xb)[k] = pack8(s[0], s[1]);
            continue;
        }
        k -= G0;
        if (k < G1) {
            size_t base = k*8;
            const float* src = (base < W1FLAT) ? (W1 + base) : (Ws1 + (base - W1FLAT));
            const float4* s = (const float4*)src;
            ((uint4*)w1b)[k] = pack8(s[0], s[1]);
            continue;
        }
        k -= G1;
        if (k < G2) {
            size_t base = k*8;
            size_t e = base/((size_t)D_*HP);
            size_t rr = base - e*(size_t)D_*HP;
            size_t drow = rr/HP, h0 = rr - drow*HP;
            const float* srow = (e < 7) ? (W2 + ((size_t)e*D_ + drow)*H_)
                                        : (Ws2 + drow*(size_t)H_);
            union { u16 h[8]; uint4 v; } u;
            #pragma unroll
            for (int q = 0; q < 8; q++) {
                size_t h = h0 + q;
                u.h[q] = (h < (size_t)H_) ? f2bf(srow[h]) : (u16)0;
            }
            ((uint4*)w2b)[k] = u.v;
            continue;
        }
        k -= G2;
        if (k < (size_t)NE*H_) {
            size_t e = k/H_, j = k - e*H_;
            b1all[k] = (e < 7) ? b1[k] : bs1[j];
        } else {
            size_t kk = k - (size_t)NE*H_;
            size_t e = kk/D_, j = kk - e*D_;
            b2all[kk] = (e < 7) ? b2[kk] : bs2[j];
        }
    }
}

// ---------------- router ----------------
__global__ void router_kernel(const float* __restrict__ x, const float* __restrict__ Wg,
                              int* __restrict__ tidx, float* __restrict__ tw,
                              float* __restrict__ probs, float* __restrict__ lse2)
{
    int wid = threadIdx.x >> 6, lane = threadIdx.x & 63;
    int n = blockIdx.x*4 + wid;
    if (n >= NTOK) return;
    float p[E_] = {};
    const float* xr = x + (size_t)n*D_;
    for (int d0 = lane*4; d0 < D_; d0 += 256) {
        float4 xv = *(const float4*)(xr + d0);
        #pragma unroll
        for (int e = 0; e < E_; e++) {
            float4 wv = *(const float4*)(Wg + e*D_ + d0);
            p[e] += xv.x*wv.x + xv.y*wv.y + xv.z*wv.z + xv.w*wv.w;
        }
    }
    #pragma unroll
    for (int e = 0; e < E_; e++) {
        float v = p[e];
        #pragma unroll
        for (int m = 32; m >= 1; m >>= 1) v += __shfl_xor(v, m);
        p[e] = v;
    }
    if (lane == 0) {
        float mx = p[0];
        #pragma unroll
        for (int e = 1; e < E_; e++) mx = fmaxf(mx, p[e]);
        float pr[E_], sum = 0.f;
        #pragma unroll
        for (int e = 0; e < E_; e++) { pr[e] = __expf(p[e]-mx); sum += pr[e]; }
        float lse = mx + logf(sum);
        int i0 = 0;
        #pragma unroll
        for (int e = 1; e < E_; e++) if (p[e] > p[i0]) i0 = e;
        int i1 = -1;
        #pragma unroll
        for (int e = 0; e < E_; e++) if (e != i0 && (i1 < 0 || p[e] > p[i1])) i1 = e;
        float g = expf(p[i1] - p[i0]);
        tidx[n*2] = i0; tidx[n*2+1] = i1;
        tw[n*2] = 1.f/(1.f+g); tw[n*2+1] = g/(1.f+g);
        float inv = 1.f/sum;
        #pragma unroll
        for (int e = 0; e < E_; e++) probs[n*8+e] = pr[e]*inv;
        lse2[n] = lse*lse;
    }
}

// ---------------- finalize: counts, offsets, loss, deterministic scatter ----------------
__global__ __launch_bounds__(512) void finalize_kernel(
    const int* __restrict__ tidx, const float* __restrict__ tw,
    const float* __restrict__ probs, const float* __restrict__ lse2,
    int* __restrict__ ci, int* __restrict__ stok, float* __restrict__ sw,
    int* __restrict__ tsl, float* __restrict__ out)
{
    __shared__ int lt[NTOK*2];
    __shared__ float psum[8];
    __shared__ float lsumS;
    __shared__ int cntS[8], offS[8];
    int t = threadIdx.x;
    if (t < 8) { psum[t] = 0.f; cntS[t] = 0; }
    if (t == 0) lsumS = 0.f;
    for (int i = t; i < NTOK*2; i += 512) lt[i] = tidx[i];
    __syncthreads();
    float lp[E_] = {}; float ll = 0.f;
    for (int n = t; n < NTOK; n += 512) {
        #pragma unroll
        for (int e = 0; e < E_; e++) lp[e] += probs[n*8+e];
        ll += lse2[n];
    }
    #pragma unroll
    for (int e = 0; e < E_; e++) atomicAdd(&psum[e], lp[e]);
    atomicAdd(&lsumS, ll);
    int wid = t >> 6, lane = t & 63;
    if (wid < 7) {
        int c = 0;
        for (int i = lane; i < NTOK*2; i += 64) c += (lt[i] == wid) ? 1 : 0;
        #pragma unroll
        for (int m = 32; m >= 1; m >>= 1) c += __shfl_xor(c, m);
        if (lane == 0) cntS[wid] = c;
    }
    __syncthreads();
    if (t == 0) {
        int o = 0;
        for (int e = 0; e < E_; e++) { offS[e] = o; o += cntS[e]; }
        offS[7] = SHARED_BASE; cntS[7] = NTOK;
        float la = 0.f;
        for (int e = 0; e < E_; e++)
            la += ((float)cntS[e] / (float)(NTOK*2)) * (psum[e] / (float)NTOK);
        out[(size_t)NTOK*D_]     = 0.01f * 7.f * la;
        out[(size_t)NTOK*D_ + 1] = 0.001f * lsumS / (float)NTOK;
        #pragma unroll
        for (int e = 0; e < 8; e++) { ci[CI_COUNT+e] = cntS[e]; ci[CI_OFF+e] = offS[e]; }
    }
    __syncthreads();
    if (wid < 7) {
        int base = offS[wid], run = 0;
        for (int c0 = 0; c0 < NTOK*2; c0 += 64) {
            bool m = (lt[c0 + lane] == wid);
            unsigned long long bal = __ballot(m);
            int pre = __popcll(bal & ((1ull << lane) - 1ull));
            if (m) {
                int i = c0 + lane;
                int s = base + run + pre;
                stok[s] = i >> 1; sw[s] = tw[i]; tsl[i] = s;
            }
            run += __popcll(bal);
        }
    } else {
        for (int n = lane; n < NTOK; n += 64) {
            stok[SHARED_BASE+n] = n; sw[SHARED_BASE+n] = 1.f;
        }
    }
}

// ---------------- GEMMs: 128x128, BK=64, dbuf LDS + counted vmcnt + XOR swizzle ----------------
#define BM 128
#define BN 128
#define BKE 64
#define TILE (BM*BKE)   // 8192 u16 = 16 KiB

__global__ __launch_bounds__(256, 2) void gemm1_kernel(
    const u16* __restrict__ xb, const u16* __restrict__ w1b,
    const float* __restrict__ b1all,
    const int* __restrict__ ci, const int* __restrict__ stok,
    u16* __restrict__ heb)
{
    __shared__ u16 As[2*TILE];
    __shared__ u16 Bs[2*TILE];
    int e = blockIdx.y >> 5, mt = blockIdx.y & 31, nt = blockIdx.x;
    int count = ci[CI_COUNT+e];
    int m0 = mt*BM;
    if (m0 >= count) return;
    int offset = ci[CI_OFF+e];
    int valid = min(BM, count - m0);

    int t = threadIdx.x, wid = t >> 6, lane = t & 63;
    int rloc = lane >> 3;             // local row 0..7 within a 1KB stage call
    int sg = (lane & 7) ^ rloc;       // pre-swizzled global 16B-chunk index
    const u16* w1e = w1b + (size_t)e*H_*D_;

    const u16* aP[4]; const u16* bP[4]; int dOff[4];
    #pragma unroll
    for (int c = 0; c < 4; c++) {
        int arow = wid*32 + c*8 + rloc;
        int ar = min(arow, valid-1);
        int tok = stok[offset + m0 + ar];
        aP[c] = xb + (size_t)tok*D_ + sg*8;
        int jg = min(nt*BN + arow, H_-1);
        bP[c] = w1e + (size_t)jg*D_ + sg*8;
        dOff[c] = (wid*32 + c*8)*BKE;        // wave-uniform LDS elem offset
    }

    int wm = (wid >> 1)*64, wn = (wid & 1)*64;
    int frow = lane & 15, kgrp = lane >> 4, swz = frow & 7;
    f32x4 acc[4][4] = {};

    #pragma unroll
    for (int c = 0; c < 4; c++) {          // prologue: stage tile 0 into buf 0
        gload_lds16(aP[c], &As[dOff[c]]);
        gload_lds16(bP[c], &Bs[dOff[c]]);
    }
    constexpr int nIter = D_ / BKE;        // 16
    for (int tt = 0; tt < nIter; ++tt) {
        int bo = (tt & 1) * TILE;
        if (tt + 1 < nIter) {
            int bo2 = TILE - bo;
            int ko = (tt + 1) * BKE;
            #pragma unroll
            for (int c = 0; c < 4; c++) {
                gload_lds16(aP[c] + ko, &As[bo2 + dOff[c]]);
                gload_lds16(bP[c] + ko, &Bs[bo2 + dOff[c]]);
            }
            asm volatile("s_waitcnt vmcnt(8)" ::: "memory");
        } else {
            asm volatile("s_waitcnt vmcnt(0)" ::: "memory");
        }
        __builtin_amdgcn_s_barrier();
        __builtin_amdgcn_sched_barrier(0);
        __builtin_amdgcn_s_setprio(1);
        #pragma unroll
        for (int s = 0; s < 2; s++) {
            int cc = ((s*4 + kgrp) ^ swz) << 3;
            bf16x8 af[4], bfr[4];
            #pragma unroll
            for (int mf = 0; mf < 4; mf++)
                af[mf] = *(const bf16x8*)&As[bo + (wm + mf*16 + frow)*BKE + cc];
            #pragma unroll
            for (int nf = 0; nf < 4; nf++)
                bfr[nf] = *(const bf16x8*)&Bs[bo + (wn + nf*16 + frow)*BKE + cc];
            #pragma unroll
            for (int mf = 0; mf < 4; mf++)
                #pragma unroll
                for (int nf = 0; nf < 4; nf++)
                    acc[mf][nf] = __builtin_amdgcn_mfma_f32_16x16x32_bf16(af[mf], bfr[nf], acc[mf][nf], 0, 0, 0);
        }
        __builtin_amdgcn_s_setprio(0);
        asm volatile("s_waitcnt lgkmcnt(0)" ::: "memory");
        __builtin_amdgcn_sched_barrier(0);
        __builtin_amdgcn_s_barrier();
    }

    int r4 = (lane >> 4)*4, cEl = lane & 15;
    #pragma unroll
    for (int mf = 0; mf < 4; mf++) {
        #pragma unroll
        for (int r = 0; r < 4; r++) {
            int row = wm + mf*16 + r4 + r;
            if (row < valid) {
                size_t rbase = (size_t)(offset + m0 + row)*HP;
                #pragma unroll
                for (int nf = 0; nf < 4; nf++) {
                    int gcol = nt*BN + wn + nf*16 + cEl;
                    float v = 0.f;
                    if (gcol < H_) {
                        v = acc[mf][nf][r] + b1all[e*H_ + gcol];
                        v = 0.5f*v*(1.f + erff(v*0.70710678118f));
                    }
                    heb[rbase + gcol] = f2bf(v);
                }
            }
        }
    }
}

__global__ __launch_bounds__(256, 2) void gemm2_kernel(
    const u16* __restrict__ heb, const u16* __restrict__ w2b,
    const float* __restrict__ b2all,
    const int* __restrict__ ci, const float* __restrict__ sw,
    float* __restrict__ y)
{
    __shared__ u16 As[2*TILE];
    __shared__ u16 Bs[2*TILE];
    int e = blockIdx.y >> 5, mt = blockIdx.y & 31, nt = blockIdx.x;
    int count = ci[CI_COUNT+e];
    int m0 = mt*BM;
    if (m0 >= count) return;
    int offset = ci[CI_OFF+e];
    int valid = min(BM, count - m0);

    int t = threadIdx.x, wid = t >> 6, lane = t & 63;
    int rloc = lane >> 3;
    int sg = (lane & 7) ^ rloc;
    const u16* w2e = w2b + (size_t)e*D_*HP;

    const u16* aP[4]; const u16* bP[4]; int dOff[4];
    #pragma unroll
    for (int c = 0; c < 4; c++) {
        int arow = wid*32 + c*8 + rloc;
        int slot = offset + m0 + arow;
        if (slot > SLOTS-1) slot = SLOTS-1;
        aP[c] = heb + (size_t)slot*HP + sg*8;
        int jg = nt*BN + arow;               // < 1024 always
        bP[c] = w2e + (size_t)jg*HP + sg*8;
        dOff[c] = (wid*32 + c*8)*BKE;
    }

    int wm = (wid >> 1)*64, wn = (wid & 1)*64;
    int frow = lane & 15, kgrp = lane >> 4, swz = frow & 7;
    f32x4 acc[4][4] = {};

    #pragma unroll
    for (int c = 0; c < 4; c++) {
        gload_lds16(aP[c], &As[dOff[c]]);
        gload_lds16(bP[c], &Bs[dOff[c]]);
    }
    constexpr int nIter = HP / BKE;        // 22
    for (int tt = 0; tt < nIter; ++tt) {
        int bo = (tt & 1) * TILE;
        if (tt + 1 < nIter) {
            int bo2 = TILE - bo;
            int ko = (tt + 1) * BKE;
            #pragma unroll
            for (int c = 0; c < 4; c++) {
                gload_lds16(aP[c] + ko, &As[bo2 + dOff[c]]);
                gload_lds16(bP[c] + ko, &Bs[bo2 + dOff[c]]);
            }
            asm volatile("s_waitcnt vmcnt(8)" ::: "memory");
        } else {
            asm volatile("s_waitcnt vmcnt(0)" ::: "memory");
        }
        __builtin_amdgcn_s_barrier();
        __builtin_amdgcn_sched_barrier(0);
        __builtin_amdgcn_s_setprio(1);
        #pragma unroll
        for (int s = 0; s < 2; s++) {
            int cc = ((s*4 + kgrp) ^ swz) << 3;
            bf16x8 af[4], bfr[4];
            #pragma unroll
            for (int mf = 0; mf < 4; mf++)
                af[mf] = *(const bf16x8*)&As[bo + (wm + mf*16 + frow)*BKE + cc];
            #pragma unroll
            for (int nf = 0; nf < 4; nf++)
                bfr[nf] = *(const bf16x8*)&Bs[bo + (wn + nf*16 + frow)*BKE + cc];
            #pragma unroll
            for (int mf = 0; mf < 4; mf++)
                #pragma unroll
                for (int nf = 0; nf < 4; nf++)
                    acc[mf][nf] = __builtin_amdgcn_mfma_f32_16x16x32_bf16(af[mf], bfr[nf], acc[mf][nf], 0, 0, 0);
        }
        __builtin_amdgcn_s_setprio(0);
        asm volatile("s_waitcnt lgkmcnt(0)" ::: "memory");
        __builtin_amdgcn_sched_barrier(0);
        __builtin_amdgcn_s_barrier();
    }

    int r4 = (lane >> 4)*4, cEl = lane & 15;
    #pragma unroll
    for (int mf = 0; mf < 4; mf++) {
        #pragma unroll
        for (int r = 0; r < 4; r++) {
            int row = wm + mf*16 + r4 + r;
            if (row < valid) {
                int slot = offset + m0 + row;
                float w = sw[slot];
                float* yrow = y + (size_t)slot*D_;
                #pragma unroll
                for (int nf = 0; nf < 4; nf++) {
                    int gcol = nt*BN + wn + nf*16 + cEl;
                    float v = acc[mf][nf][r] + b2all[e*D_ + gcol];
                    yrow[gcol] = w*v;
                }
            }
        }
    }
}

// ---------------- combine: out[n] = y[s0] + y[s1] + y[shared+n] ----------------
__global__ __launch_bounds__(256) void combine_kernel(
    const float* __restrict__ y, const int* __restrict__ tsl,
    float* __restrict__ out)
{
    int n = blockIdx.x;
    int t = threadIdx.x;
    int s0 = tsl[2*n], s1 = tsl[2*n+1];
    const float4* y0 = (const float4*)(y + (size_t)s0*D_);
    const float4* y1 = (const float4*)(y + (size_t)s1*D_);
    const float4* ys = (const float4*)(y + (size_t)(SHARED_BASE+n)*D_);
    float4 a = y0[t], b = y1[t], c = ys[t];
    float4 r;
    r.x = a.x + b.x + c.x;
    r.y = a.y + b.y + c.y;
    r.z = a.z + b.z + c.z;
    r.w = a.w + b.w + c.w;
    ((float4*)(out + (size_t)n*D_))[t] = r;
}

extern "C" void kernel_launch(void* const* d_in, const int* in_sizes, int n_in,
                              void* d_out, int out_size, void* d_ws, size_t ws_size,
                              hipStream_t stream)
{
    const float* x   = (const float*)d_in[0];
    const float* Wg  = (const float*)d_in[1];
    const float* W1  = (const float*)d_in[2];
    const float* b1  = (const float*)d_in[3];
    const float* W2  = (const float*)d_in[4];
    const float* b2  = (const float*)d_in[5];
    const float* Ws1 = (const float*)d_in[6];
    const float* bs1 = (const float*)d_in[7];
    const float* Ws2 = (const float*)d_in[8];
    const float* bs2 = (const float*)d_in[9];
    float* out = (float*)d_out;
    char* ws = (char*)d_ws;

    int*   ci    = (int*)(ws + WS_CTRL);
    int*   tidx  = (int*)(ws + WS_TIDX);
    float* tw    = (float*)(ws + WS_TW);
    float* probs = (float*)(ws + WS_PROB);
    float* lse2  = (float*)(ws + WS_LSE2);
    int*   stok  = (int*)(ws + WS_STOK);
    float* sw    = (float*)(ws + WS_SW);
    int*   tsl   = (int*)(ws + WS_TSL);
    float* b1all = (float*)(ws + WS_B1);
    float* b2all = (float*)(ws + WS_B2);
    u16*   xb    = (u16*)(ws + WS_XB);
    u16*   w1b   = (u16*)(ws + WS_W1B);
    u16*   w2b   = (u16*)(ws + WS_W2B);
    u16*   heb   = (u16*)(ws + WS_HEB);
    float* y     = (float*)(ws + WS_Y);

    convert_kernel<<<2048, 256, 0, stream>>>(x, W1, Ws1, W2, Ws2, b1, bs1, b2, bs2,
                                             xb, w1b, w2b, b1all, b2all);
    router_kernel<<<NTOK/4, 256, 0, stream>>>(x, Wg, tidx, tw, probs, lse2);
    finalize_kernel<<<1, 512, 0, stream>>>(tidx, tw, probs, lse2, ci, stok, sw, tsl, out);

    dim3 g1(HP/BN, NE*32);   // 11 x 256
    gemm1_kernel<<<g1, 256, 0, stream>>>(xb, w1b, b1all, ci, stok, heb);
    dim3 g2(D_/BN, NE*32);   // 8 x 256
    gemm2_kernel<<<g2, 256, 0, stream>>>(heb, w2b, b2all, ci, sw, y);
    combine_kernel<<<NTOK, 256, 0, stream>>>(y, tsl, out);
}

// Round 4
// 190.427 us; speedup vs baseline: 1.1386x; 1.1386x over previous
//
#include <hip/hip_runtime.h>
#include <hip/hip_bf16.h>
#include <math.h>

typedef unsigned short u16;
typedef __attribute__((ext_vector_type(8))) short bf16x8;
typedef __attribute__((ext_vector_type(4))) float f32x4;

constexpr int D_ = 1024;
constexpr int H_ = 1365;
constexpr int E_ = 7;
constexpr int NTOK = 2048;
constexpr int HP = 1408;          // H padded to multiple of 64 (BK)
constexpr int NE = 8;             // 7 routed + 1 shared
constexpr int SHARED_BASE = 4096;
constexpr int SLOTS = 6144;

#define CI_COUNT 0
#define CI_OFF   8

constexpr size_t WS_CTRL = 0;
constexpr size_t WS_TIDX = 256;
constexpr size_t WS_TW   = WS_TIDX + (size_t)NTOK*2*4;
constexpr size_t WS_PROB = WS_TW   + (size_t)NTOK*2*4;
constexpr size_t WS_LSE2 = WS_PROB + (size_t)NTOK*8*4;
constexpr size_t WS_STOK = WS_LSE2 + (size_t)NTOK*4;
constexpr size_t WS_SW   = WS_STOK + (size_t)SLOTS*4;
constexpr size_t WS_TSL  = WS_SW   + (size_t)SLOTS*4;
constexpr size_t WS_B1   = WS_TSL  + (size_t)NTOK*2*4;
constexpr size_t WS_B2   = WS_B1   + (size_t)NE*H_*4;
constexpr size_t WS_XB   = ((WS_B2 + (size_t)NE*D_*4) + 255) & ~(size_t)255;
constexpr size_t WS_W1B  = WS_XB  + (size_t)NTOK*D_*2;
constexpr size_t WS_W2B  = WS_W1B + (size_t)NE*H_*D_*2;
constexpr size_t WS_HEB  = WS_W2B + (size_t)NE*D_*HP*2;
constexpr size_t WS_Y    = WS_XB;   // y[SLOTS][D] fp32 aliases xb+w1b (dead after gemm1)

__device__ __forceinline__ u16 f2bf(float f) {
    __hip_bfloat16 h = __float2bfloat16(f);
    return __builtin_bit_cast(u16, h);
}

__device__ __forceinline__ void gload_lds16(const u16* g, u16* l) {
    __builtin_amdgcn_global_load_lds(
        (const __attribute__((address_space(1))) void*)g,
        (__attribute__((address_space(3))) void*)l, 16, 0, 0);
}

__device__ __forceinline__ uint4 pack8(float4 a, float4 b) {
    union { u16 h[8]; uint4 v; } u;
    u.h[0]=f2bf(a.x); u.h[1]=f2bf(a.y); u.h[2]=f2bf(a.z); u.h[3]=f2bf(a.w);
    u.h[4]=f2bf(b.x); u.h[5]=f2bf(b.y); u.h[6]=f2bf(b.z); u.h[7]=f2bf(b.w);
    return u.v;
}

// ---------------- convert fp32 -> bf16 staging buffers ----------------
__global__ void convert_kernel(const float* __restrict__ x,
                               const float* __restrict__ W1, const float* __restrict__ Ws1,
                               const float* __restrict__ W2, const float* __restrict__ Ws2,
                               const float* __restrict__ b1, const float* __restrict__ bs1,
                               const float* __restrict__ b2, const float* __restrict__ bs2,
                               u16* __restrict__ xb, u16* __restrict__ w1b, u16* __restrict__ w2b,
                               float* __restrict__ b1all, float* __restrict__ b2all)
{
    const size_t G0 = (size_t)NTOK*D_/8;
    const size_t G1 = (size_t)NE*H_*D_/8;
    const size_t G2 = (size_t)NE*D_*HP/8;
    const size_t W1FLAT = (size_t)7*H_*D_;
    const size_t SB = (size_t)NE*H_ + (size_t)NE*D_;
    const size_t total = G0+G1+G2+SB;
    for (size_t i = blockIdx.x*(size_t)blockDim.x + threadIdx.x; i < total;
         i += (size_t)gridDim.x*blockDim.x) {
        size_t k = i;
        if (k < G0) {
            const float4* s = (const float4*)x + k*2;
            ((uint4*)xb)[k] = pack8(s[0], s[1]);
            continue;
        }
        k -= G0;
        if (k < G1) {
            size_t base = k*8;
            const float* src = (base < W1FLAT) ? (W1 + base) : (Ws1 + (base - W1FLAT));
            const float4* s = (const float4*)src;
            ((uint4*)w1b)[k] = pack8(s[0], s[1]);
            continue;
        }
        k -= G1;
        if (k < G2) {
            size_t base = k*8;
            size_t e = base/((size_t)D_*HP);
            size_t rr = base - e*(size_t)D_*HP;
            size_t drow = rr/HP, h0 = rr - drow*HP;
            const float* srow = (e < 7) ? (W2 + ((size_t)e*D_ + drow)*H_)
                                        : (Ws2 + drow*(size_t)H_);
            union { u16 h[8]; uint4 v; } u;
            #pragma unroll
            for (int q = 0; q < 8; q++) {
                size_t h = h0 + q;
                u.h[q] = (h < (size_t)H_) ? f2bf(srow[h]) : (u16)0;
            }
            ((uint4*)w2b)[k] = u.v;
            continue;
        }
        k -= G2;
        if (k < (size_t)NE*H_) {
            size_t e = k/H_, j = k - e*H_;
            b1all[k] = (e < 7) ? b1[k] : bs1[j];
        } else {
            size_t kk = k - (size_t)NE*H_;
            size_t e = kk/D_, j = kk - e*D_;
            b2all[kk] = (e < 7) ? b2[kk] : bs2[j];
        }
    }
}

// ---------------- router ----------------
__global__ void router_kernel(const float* __restrict__ x, const float* __restrict__ Wg,
                              int* __restrict__ tidx, float* __restrict__ tw,
                              float* __restrict__ probs, float* __restrict__ lse2)
{
    int wid = threadIdx.x >> 6, lane = threadIdx.x & 63;
    int n = blockIdx.x*4 + wid;
    if (n >= NTOK) return;
    float p[E_] = {};
    const float* xr = x + (size_t)n*D_;
    for (int d0 = lane*4; d0 < D_; d0 += 256) {
        float4 xv = *(const float4*)(xr + d0);
        #pragma unroll
        for (int e = 0; e < E_; e++) {
            float4 wv = *(const float4*)(Wg + e*D_ + d0);
            p[e] += xv.x*wv.x + xv.y*wv.y + xv.z*wv.z + xv.w*wv.w;
        }
    }
    #pragma unroll
    for (int e = 0; e < E_; e++) {
        float v = p[e];
        #pragma unroll
        for (int m = 32; m >= 1; m >>= 1) v += __shfl_xor(v, m);
        p[e] = v;
    }
    if (lane == 0) {
        float mx = p[0];
        #pragma unroll
        for (int e = 1; e < E_; e++) mx = fmaxf(mx, p[e]);
        float pr[E_], sum = 0.f;
        #pragma unroll
        for (int e = 0; e < E_; e++) { pr[e] = __expf(p[e]-mx); sum += pr[e]; }
        float lse = mx + logf(sum);
        int i0 = 0;
        #pragma unroll
        for (int e = 1; e < E_; e++) if (p[e] > p[i0]) i0 = e;
        int i1 = -1;
        #pragma unroll
        for (int e = 0; e < E_; e++) if (e != i0 && (i1 < 0 || p[e] > p[i1])) i1 = e;
        float g = expf(p[i1] - p[i0]);
        tidx[n*2] = i0; tidx[n*2+1] = i1;
        tw[n*2] = 1.f/(1.f+g); tw[n*2+1] = g/(1.f+g);
        float inv = 1.f/sum;
        #pragma unroll
        for (int e = 0; e < E_; e++) probs[n*8+e] = pr[e]*inv;
        lse2[n] = lse*lse;
    }
}

// ---------------- finalize: counts, offsets, loss, deterministic scatter ----------------
__global__ __launch_bounds__(512) void finalize_kernel(
    const int* __restrict__ tidx, const float* __restrict__ tw,
    const float* __restrict__ probs, const float* __restrict__ lse2,
    int* __restrict__ ci, int* __restrict__ stok, float* __restrict__ sw,
    int* __restrict__ tsl, float* __restrict__ out)
{
    __shared__ int lt[NTOK*2];
    __shared__ float psum[8];
    __shared__ float lsumS;
    __shared__ int cntS[8], offS[8];
    int t = threadIdx.x;
    if (t < 8) { psum[t] = 0.f; cntS[t] = 0; }
    if (t == 0) lsumS = 0.f;
    for (int i = t; i < NTOK*2; i += 512) lt[i] = tidx[i];
    __syncthreads();
    float lp[E_] = {}; float ll = 0.f;
    for (int n = t; n < NTOK; n += 512) {
        #pragma unroll
        for (int e = 0; e < E_; e++) lp[e] += probs[n*8+e];
        ll += lse2[n];
    }
    #pragma unroll
    for (int e = 0; e < E_; e++) atomicAdd(&psum[e], lp[e]);
    atomicAdd(&lsumS, ll);
    int wid = t >> 6, lane = t & 63;
    if (wid < 7) {
        int c = 0;
        for (int i = lane; i < NTOK*2; i += 64) c += (lt[i] == wid) ? 1 : 0;
        #pragma unroll
        for (int m = 32; m >= 1; m >>= 1) c += __shfl_xor(c, m);
        if (lane == 0) cntS[wid] = c;
    }
    __syncthreads();
    if (t == 0) {
        int o = 0;
        for (int e = 0; e < E_; e++) { offS[e] = o; o += cntS[e]; }
        offS[7] = SHARED_BASE; cntS[7] = NTOK;
        float la = 0.f;
        for (int e = 0; e < E_; e++)
            la += ((float)cntS[e] / (float)(NTOK*2)) * (psum[e] / (float)NTOK);
        out[(size_t)NTOK*D_]     = 0.01f * 7.f * la;
        out[(size_t)NTOK*D_ + 1] = 0.001f * lsumS / (float)NTOK;
        #pragma unroll
        for (int e = 0; e < 8; e++) { ci[CI_COUNT+e] = cntS[e]; ci[CI_OFF+e] = offS[e]; }
    }
    __syncthreads();
    if (wid < 7) {
        int base = offS[wid], run = 0;
        for (int c0 = 0; c0 < NTOK*2; c0 += 64) {
            bool m = (lt[c0 + lane] == wid);
            unsigned long long bal = __ballot(m);
            int pre = __popcll(bal & ((1ull << lane) - 1ull));
            if (m) {
                int i = c0 + lane;
                int s = base + run + pre;
                stok[s] = i >> 1; sw[s] = tw[i]; tsl[i] = s;
            }
            run += __popcll(bal);
        }
    } else {
        for (int n = lane; n < NTOK; n += 64) {
            stok[SHARED_BASE+n] = n; sw[SHARED_BASE+n] = 1.f;
        }
    }
}

// ---------------- GEMMs: expert->XCD pinned grid, 128x128, BK=64, dbuf + vmcnt ----------------
#define BM 128
#define BN 128
#define BKE 64
#define TILE (BM*BKE)   // 8192 u16 = 16 KiB

// grid.x = 8 (expert = XCD via linear%8); shared expert (e=7) striped mt = s*8 + x.
__device__ __forceinline__ bool map_tile(int x, int y, int ntiles, int* e, int* mt, int* nt) {
    int routedY = 16 * ntiles;
    if (y < routedY) {
        if (x == 7) return false;      // no routed expert 7
        *e = x; *mt = y / ntiles; *nt = y % ntiles;
    } else {
        int yy = y - routedY;
        *e = 7; *mt = (yy / ntiles) * 8 + x; *nt = yy % ntiles;
    }
    return true;
}

__global__ __launch_bounds__(256, 2) void gemm1_kernel(
    const u16* __restrict__ xb, const u16* __restrict__ w1b,
    const float* __restrict__ b1all,
    const int* __restrict__ ci, const int* __restrict__ stok,
    u16* __restrict__ heb)
{
    __shared__ u16 As[2*TILE];
    __shared__ u16 Bs[2*TILE];
    int e, mt, nt;
    if (!map_tile(blockIdx.x, blockIdx.y, 11, &e, &mt, &nt)) return;
    int count = ci[CI_COUNT+e];
    int m0 = mt*BM;
    if (m0 >= count) return;
    int offset = ci[CI_OFF+e];
    int valid = min(BM, count - m0);

    int t = threadIdx.x, wid = t >> 6, lane = t & 63;
    int rloc = lane >> 3;             // local row 0..7 within a 1KB stage call
    int sg = (lane & 7) ^ rloc;       // pre-swizzled global 16B-chunk index
    const u16* w1e = w1b + (size_t)e*H_*D_;

    const u16* aP[4]; const u16* bP[4]; int dOff[4];
    #pragma unroll
    for (int c = 0; c < 4; c++) {
        int arow = wid*32 + c*8 + rloc;
        int ar = min(arow, valid-1);
        int tok = stok[offset + m0 + ar];
        aP[c] = xb + (size_t)tok*D_ + sg*8;
        int jg = min(nt*BN + arow, H_-1);
        bP[c] = w1e + (size_t)jg*D_ + sg*8;
        dOff[c] = (wid*32 + c*8)*BKE;        // wave-uniform LDS elem offset
    }

    int wm = (wid >> 1)*64, wn = (wid & 1)*64;
    int frow = lane & 15, kgrp = lane >> 4, swz = frow & 7;
    f32x4 acc[4][4] = {};

    #pragma unroll
    for (int c = 0; c < 4; c++) {          // prologue: stage tile 0 into buf 0
        gload_lds16(aP[c], &As[dOff[c]]);
        gload_lds16(bP[c], &Bs[dOff[c]]);
    }
    constexpr int nIter = D_ / BKE;        // 16
    for (int tt = 0; tt < nIter; ++tt) {
        int bo = (tt & 1) * TILE;
        if (tt + 1 < nIter) {
            int bo2 = TILE - bo;
            int ko = (tt + 1) * BKE;
            #pragma unroll
            for (int c = 0; c < 4; c++) {
                gload_lds16(aP[c] + ko, &As[bo2 + dOff[c]]);
                gload_lds16(bP[c] + ko, &Bs[bo2 + dOff[c]]);
            }
            asm volatile("s_waitcnt vmcnt(8)" ::: "memory");
        } else {
            asm volatile("s_waitcnt vmcnt(0)" ::: "memory");
        }
        __builtin_amdgcn_s_barrier();
        __builtin_amdgcn_sched_barrier(0);
        __builtin_amdgcn_s_setprio(1);
        #pragma unroll
        for (int s = 0; s < 2; s++) {
            int cc = ((s*4 + kgrp) ^ swz) << 3;
            bf16x8 af[4], bfr[4];
            #pragma unroll
            for (int mf = 0; mf < 4; mf++)
                af[mf] = *(const bf16x8*)&As[bo + (wm + mf*16 + frow)*BKE + cc];
            #pragma unroll
            for (int nf = 0; nf < 4; nf++)
                bfr[nf] = *(const bf16x8*)&Bs[bo + (wn + nf*16 + frow)*BKE + cc];
            #pragma unroll
            for (int mf = 0; mf < 4; mf++)
                #pragma unroll
                for (int nf = 0; nf < 4; nf++)
                    acc[mf][nf] = __builtin_amdgcn_mfma_f32_16x16x32_bf16(af[mf], bfr[nf], acc[mf][nf], 0, 0, 0);
        }
        __builtin_amdgcn_s_setprio(0);
        asm volatile("s_waitcnt lgkmcnt(0)" ::: "memory");
        __builtin_amdgcn_sched_barrier(0);
        __builtin_amdgcn_s_barrier();
    }

    int r4 = (lane >> 4)*4, cEl = lane & 15;
    #pragma unroll
    for (int mf = 0; mf < 4; mf++) {
        #pragma unroll
        for (int r = 0; r < 4; r++) {
            int row = wm + mf*16 + r4 + r;
            if (row < valid) {
                size_t rbase = (size_t)(offset + m0 + row)*HP;
                #pragma unroll
                for (int nf = 0; nf < 4; nf++) {
                    int gcol = nt*BN + wn + nf*16 + cEl;
                    float v = 0.f;
                    if (gcol < H_) {
                        v = acc[mf][nf][r] + b1all[e*H_ + gcol];
                        v = 0.5f*v*(1.f + erff(v*0.70710678118f));
                    }
                    heb[rbase + gcol] = f2bf(v);
                }
            }
        }
    }
}

__global__ __launch_bounds__(256, 2) void gemm2_kernel(
    const u16* __restrict__ heb, const u16* __restrict__ w2b,
    const float* __restrict__ b2all,
    const int* __restrict__ ci, const float* __restrict__ sw,
    float* __restrict__ y)
{
    __shared__ u16 As[2*TILE];
    __shared__ u16 Bs[2*TILE];
    int e, mt, nt;
    if (!map_tile(blockIdx.x, blockIdx.y, 8, &e, &mt, &nt)) return;
    int count = ci[CI_COUNT+e];
    int m0 = mt*BM;
    if (m0 >= count) return;
    int offset = ci[CI_OFF+e];
    int valid = min(BM, count - m0);

    int t = threadIdx.x, wid = t >> 6, lane = t & 63;
    int rloc = lane >> 3;
    int sg = (lane & 7) ^ rloc;
    const u16* w2e = w2b + (size_t)e*D_*HP;

    const u16* aP[4]; const u16* bP[4]; int dOff[4];
    #pragma unroll
    for (int c = 0; c < 4; c++) {
        int arow = wid*32 + c*8 + rloc;
        int slot = offset + m0 + arow;
        if (slot > SLOTS-1) slot = SLOTS-1;
        aP[c] = heb + (size_t)slot*HP + sg*8;
        int jg = nt*BN + arow;               // < 1024 always
        bP[c] = w2e + (size_t)jg*HP + sg*8;
        dOff[c] = (wid*32 + c*8)*BKE;
    }

    int wm = (wid >> 1)*64, wn = (wid & 1)*64;
    int frow = lane & 15, kgrp = lane >> 4, swz = frow & 7;
    f32x4 acc[4][4] = {};

    #pragma unroll
    for (int c = 0; c < 4; c++) {
        gload_lds16(aP[c], &As[dOff[c]]);
        gload_lds16(bP[c], &Bs[dOff[c]]);
    }
    constexpr int nIter = HP / BKE;        // 22
    for (int tt = 0; tt < nIter; ++tt) {
        int bo = (tt & 1) * TILE;
        if (tt + 1 < nIter) {
            int bo2 = TILE - bo;
            int ko = (tt + 1) * BKE;
            #pragma unroll
            for (int c = 0; c < 4; c++) {
                gload_lds16(aP[c] + ko, &As[bo2 + dOff[c]]);
                gload_lds16(bP[c] + ko, &Bs[bo2 + dOff[c]]);
            }
            asm volatile("s_waitcnt vmcnt(8)" ::: "memory");
        } else {
            asm volatile("s_waitcnt vmcnt(0)" ::: "memory");
        }
        __builtin_amdgcn_s_barrier();
        __builtin_amdgcn_sched_barrier(0);
        __builtin_amdgcn_s_setprio(1);
        #pragma unroll
        for (int s = 0; s < 2; s++) {
            int cc = ((s*4 + kgrp) ^ swz) << 3;
            bf16x8 af[4], bfr[4];
            #pragma unroll
            for (int mf = 0; mf < 4; mf++)
                af[mf] = *(const bf16x8*)&As[bo + (wm + mf*16 + frow)*BKE + cc];
            #pragma unroll
            for (int nf = 0; nf < 4; nf++)
                bfr[nf] = *(const bf16x8*)&Bs[bo + (wn + nf*16 + frow)*BKE + cc];
            #pragma unroll
            for (int mf = 0; mf < 4; mf++)
                #pragma unroll
                for (int nf = 0; nf < 4; nf++)
                    acc[mf][nf] = __builtin_amdgcn_mfma_f32_16x16x32_bf16(af[mf], bfr[nf], acc[mf][nf], 0, 0, 0);
        }
        __builtin_amdgcn_s_setprio(0);
        asm volatile("s_waitcnt lgkmcnt(0)" ::: "memory");
        __builtin_amdgcn_sched_barrier(0);
        __builtin_amdgcn_s_barrier();
    }

    int r4 = (lane >> 4)*4, cEl = lane & 15;
    #pragma unroll
    for (int mf = 0; mf < 4; mf++) {
        #pragma unroll
        for (int r = 0; r < 4; r++) {
            int row = wm + mf*16 + r4 + r;
            if (row < valid) {
                int slot = offset + m0 + row;
                float w = sw[slot];
                float* yrow = y + (size_t)slot*D_;
                #pragma unroll
                for (int nf = 0; nf < 4; nf++) {
                    int gcol = nt*BN + wn + nf*16 + cEl;
                    float v = acc[mf][nf][r] + b2all[e*D_ + gcol];
                    yrow[gcol] = w*v;
                }
            }
        }
    }
}

// ---------------- combine: out[n] = y[s0] + y[s1] + y[shared+n] ----------------
__global__ __launch_bounds__(256) void combine_kernel(
    const float* __restrict__ y, const int* __restrict__ tsl,
    float* __restrict__ out)
{
    int n = blockIdx.x;
    int t = threadIdx.x;
    int s0 = tsl[2*n], s1 = tsl[2*n+1];
    const float4* y0 = (const float4*)(y + (size_t)s0*D_);
    const float4* y1 = (const float4*)(y + (size_t)s1*D_);
    const float4* ys = (const float4*)(y + (size_t)(SHARED_BASE+n)*D_);
    float4 a = y0[t], b = y1[t], c = ys[t];
    float4 r;
    r.x = a.x + b.x + c.x;
    r.y = a.y + b.y + c.y;
    r.z = a.z + b.z + c.z;
    r.w = a.w + b.w + c.w;
    ((float4*)(out + (size_t)n*D_))[t] = r;
}

extern "C" void kernel_launch(void* const* d_in, const int* in_sizes, int n_in,
                              void* d_out, int out_size, void* d_ws, size_t ws_size,
                              hipStream_t stream)
{
    const float* x   = (const float*)d_in[0];
    const float* Wg  = (const float*)d_in[1];
    const float* W1  = (const float*)d_in[2];
    const float* b1  = (const float*)d_in[3];
    const float* W2  = (const float*)d_in[4];
    const float* b2  = (const float*)d_in[5];
    const float* Ws1 = (const float*)d_in[6];
    const float* bs1 = (const float*)d_in[7];
    const float* Ws2 = (const float*)d_in[8];
    const float* bs2 = (const float*)d_in[9];
    float* out = (float*)d_out;
    char* ws = (char*)d_ws;

    int*   ci    = (int*)(ws + WS_CTRL);
    int*   tidx  = (int*)(ws + WS_TIDX);
    float* tw    = (float*)(ws + WS_TW);
    float* probs = (float*)(ws + WS_PROB);
    float* lse2  = (float*)(ws + WS_LSE2);
    int*   stok  = (int*)(ws + WS_STOK);
    float* sw    = (float*)(ws + WS_SW);
    int*   tsl   = (int*)(ws + WS_TSL);
    float* b1all = (float*)(ws + WS_B1);
    float* b2all = (float*)(ws + WS_B2);
    u16*   xb    = (u16*)(ws + WS_XB);
    u16*   w1b   = (u16*)(ws + WS_W1B);
    u16*   w2b   = (u16*)(ws + WS_W2B);
    u16*   heb   = (u16*)(ws + WS_HEB);
    float* y     = (float*)(ws + WS_Y);

    convert_kernel<<<2048, 256, 0, stream>>>(x, W1, Ws1, W2, Ws2, b1, bs1, b2, bs2,
                                             xb, w1b, w2b, b1all, b2all);
    router_kernel<<<NTOK/4, 256, 0, stream>>>(x, Wg, tidx, tw, probs, lse2);
    finalize_kernel<<<1, 512, 0, stream>>>(tidx, tw, probs, lse2, ci, stok, sw, tsl, out);

    // expert -> XCD pinned grids: grid.x = 8 = #XCDs, linear%8 == blockIdx.x == expert
    dim3 g1(8, 16*11 + 2*11);   // routed: 16 mt x 11 nt; shared: 2 stripes x 11 nt
    gemm1_kernel<<<g1, 256, 0, stream>>>(xb, w1b, b1all, ci, stok, heb);
    dim3 g2(8, 16*8 + 2*8);     // routed: 16 mt x 8 nt; shared: 2 stripes x 8 nt
    gemm2_kernel<<<g2, 256, 0, stream>>>(heb, w2b, b2all, ci, sw, y);
    combine_kernel<<<NTOK, 256, 0, stream>>>(y, tsl, out);
}